// Round 5
// baseline (4487.321 us; speedup 1.0000x reference)
//
#include <hip/hip_runtime.h>
#include <hip/hip_bf16.h>

// VQ: z [16,256,32,32] f32, emb [8192,256] f32.
// N = 16384 rows (b,h,w), C = 256, K = 8192.
// d_out is FLOAT32 (reference outputs f32; forensically confirmed r1/r3/r4):
//   z_q [16,256,32,32] f32 @ 0, loss [16,32,32,256] f32 @ 4194304, idx (as f32) @ 8388608.

#define NROWS 16384
#define KCODES 8192

// ---------------- K0a: zz[n] = sum_c z[n][c]^2 ----------------
__global__ void k_zz(const float* __restrict__ z, float* __restrict__ zz){
  __shared__ float p[256];
  const int t  = threadIdx.x;
  const int nl = t & 63, q = t >> 6;
  const int n  = blockIdx.x * 64 + nl;
  const int b  = n >> 10, hw = n & 1023;
  const float* zp = z + b * 262144 + hw;
  float s = 0.f;
  const int c0 = q * 64;
  #pragma unroll 8
  for (int i = 0; i < 64; ++i){
    float v = zp[(c0 + i) * 1024];
    s = fmaf(v, v, s);
  }
  p[t] = s;
  __syncthreads();
  if (q == 0){
    float tot = ((p[nl] + p[nl + 64]) + p[nl + 128]) + p[nl + 192];
    zz[n] = tot;
  }
}

// ---------------- K0b: ee[k] = sum_c emb[k][c]^2 ----------------
__global__ void k_ee(const float* __restrict__ emb, float* __restrict__ ee){
  const int t = threadIdx.x;
  const int k = blockIdx.x * 4 + (t >> 6);
  const int lane = t & 63;
  const float* ep = emb + k * 256;
  float s = 0.f;
  #pragma unroll
  for (int j = 0; j < 4; ++j){
    float v = ep[lane + 64 * j];
    s = fmaf(v, v, s);
  }
  #pragma unroll
  for (int off = 32; off; off >>= 1) s += __shfl_down(s, off);
  if (lane == 0) ee[k] = s;
}

// ---------------- K1: argmin over codes (single-buffered) ----------------
// 512 blocks: rowblock = bid>>2 (128 rows), quarter = bid&3 (2048 codes).
// 256 threads: tx = tid&15 (codes, 8 each), ty = tid>>4 (rows, 8 each).
__global__ void k_argmin(const float* __restrict__ z, const float* __restrict__ emb,
                         const float* __restrict__ zz, const float* __restrict__ ee,
                         float* __restrict__ candd, int* __restrict__ candi){
  __shared__ float zs[128][36];
  __shared__ float es[128][36];

  const int tid = threadIdx.x;
  const int bid = blockIdx.x;
  const int rowblock = bid >> 2;
  const int quarter  = bid & 3;
  const int n0     = rowblock * 128;
  const int k0base = quarter * 2048;
  const int tx = tid & 15, ty = tid >> 4;

  const int b = n0 >> 10, hw0 = n0 & 1023;      // all 128 rows share b (128 | 1024)
  const float* zb = z + b * 262144 + hw0;       // + c*1024 + r

  float acc[8][8];
  float best[8];
  int   bidx[8];
  float zzr[8];
  #pragma unroll
  for (int i = 0; i < 8; ++i){
    best[i] = 3.0e38f; bidx[i] = 0;             // in-range init
    zzr[i]  = zz[n0 + ty * 8 + i];
    #pragma unroll
    for (int j = 0; j < 8; ++j) acc[i][j] = 0.f;
  }

  for (int kt = 0; kt < 16; ++kt){
    const int kk0 = k0base + kt * 128;
    for (int cc = 0; cc < 8; ++cc){
      const int cbase = cc * 32;
      float4 zr[4], er[4];
      #pragma unroll
      for (int l = 0; l < 4; ++l){
        const int idx = tid + 256 * l;
        const int c = idx >> 5, ng = idx & 31;
        zr[l] = *reinterpret_cast<const float4*>(zb + (cbase + c) * 1024 + ng * 4);
      }
      #pragma unroll
      for (int l = 0; l < 4; ++l){
        const int idx = tid + 256 * l;
        const int k = idx >> 3, cg = idx & 7;
        er[l] = *reinterpret_cast<const float4*>(emb + (kk0 + k) * 256 + cbase + cg * 4);
      }
      __syncthreads();
      #pragma unroll
      for (int l = 0; l < 4; ++l){
        const int idx = tid + 256 * l;
        const int c = idx >> 5, ng = idx & 31;
        const float v[4] = {zr[l].x, zr[l].y, zr[l].z, zr[l].w};
        #pragma unroll
        for (int m = 0; m < 4; ++m){
          const int r = ng * 4 + m;
          const int g = (r >> 2) & 7;
          zs[r][4 * ((c >> 2) ^ g) + (c & 3)] = v[m];
        }
      }
      #pragma unroll
      for (int l = 0; l < 4; ++l){
        const int idx = tid + 256 * l;
        const int k = idx >> 3, cg = idx & 7;
        const int cgs = cg ^ ((k >> 3) & 7);
        *reinterpret_cast<float4*>(&es[k][cgs * 4]) = er[l];
      }
      __syncthreads();
      #pragma unroll 2
      for (int s4 = 0; s4 < 8; ++s4){
        float4 zv[8], ev[8];
        #pragma unroll
        for (int i = 0; i < 8; ++i){
          const int r = ty * 8 + i;
          const int g = (r >> 2) & 7;
          zv[i] = *reinterpret_cast<const float4*>(&zs[r][4 * (s4 ^ g)]);
        }
        #pragma unroll
        for (int j = 0; j < 8; ++j){
          const int k = tx * 8 + j;
          ev[j] = *reinterpret_cast<const float4*>(&es[k][4 * (s4 ^ (tx & 7))]);
        }
        #pragma unroll
        for (int i = 0; i < 8; ++i){
          #pragma unroll
          for (int j = 0; j < 8; ++j){
            float a = acc[i][j];
            a = fmaf(zv[i].x, ev[j].x, a);
            a = fmaf(zv[i].y, ev[j].y, a);
            a = fmaf(zv[i].z, ev[j].z, a);
            a = fmaf(zv[i].w, ev[j].w, a);
            acc[i][j] = a;
          }
        }
      }
    }
    // distances + running argmin for this k-tile
    float eeg[8];
    #pragma unroll
    for (int j = 0; j < 8; ++j) eeg[j] = ee[kk0 + tx * 8 + j];
    #pragma unroll
    for (int i = 0; i < 8; ++i){
      #pragma unroll
      for (int j = 0; j < 8; ++j){
        // EXACT reference op order: fl(fl(zz+ee) - fl(2*dot)); 2*dot exact.
        const float t1 = zzr[i] + eeg[j];
        const float d  = t1 - 2.0f * acc[i][j];
        const int kidx = kk0 + tx * 8 + j;
        if (d < best[i]) { best[i] = d; bidx[i] = kidx; }  // strict <: lowest index wins ties
        acc[i][j] = 0.f;
      }
    }
  }

  // cross-tx reduction per row (16 candidates/row), tie -> lower index
  __syncthreads();
  float* redd = &zs[0][0];
  int*   redi = reinterpret_cast<int*>(&es[0][0]);
  #pragma unroll
  for (int i = 0; i < 8; ++i){
    const int r = ty * 8 + i;
    redd[r * 16 + tx] = best[i];
    redi[r * 16 + tx] = bidx[i];
  }
  __syncthreads();
  if (tid < 128){
    const int r = tid;
    float bd = redd[r * 16];
    int   bi = redi[r * 16];
    #pragma unroll
    for (int t2 = 1; t2 < 16; ++t2){
      const float d = redd[r * 16 + t2];
      const int  ii = redi[r * 16 + t2];
      if (d < bd || (d == bd && ii < bi)) { bd = d; bi = ii; }
    }
    candd[(n0 + r) * 4 + quarter] = bd;
    candi[(n0 + r) * 4 + quarter] = bi;
  }
}

// ---------------- K2: pick winner across 4 K-quarters ----------------
__global__ void k_pick(const float* __restrict__ candd, const int* __restrict__ candi,
                       int* __restrict__ idx32, float* __restrict__ out_idx){
  const int n = blockIdx.x * 256 + threadIdx.x;
  float bd = candd[n * 4];
  int   bi = candi[n * 4];
  #pragma unroll
  for (int t = 1; t < 4; ++t){
    const float d = candd[n * 4 + t];
    const int  ii = candi[n * 4 + t];
    if (d < bd) { bd = d; bi = ii; }   // quarters ascend in k: tie keeps lower index
  }
  bi &= (KCODES - 1);
  idx32[n] = bi;
  out_idx[n] = (float)bi;              // f32 output
}

// ---------------- K3: z_q output, f32, [b,c,h,w] layout ----------------
__global__ void k_zq(const float* __restrict__ z, const float* __restrict__ emb,
                     const int* __restrict__ idx32, float* __restrict__ out_zq){
  const int bid = blockIdx.x;                 // 4096 = 16 b * 256 c
  const int b = bid >> 8, c = bid & 255;
  const int t = threadIdx.x;
  const float* zp = z + b * 262144 + c * 1024;
  #pragma unroll
  for (int l = 0; l < 4; ++l){
    const int hw = t + 256 * l;
    const float zv = zp[hw];
    const int  ii  = idx32[b * 1024 + hw] & (KCODES - 1);
    const float e  = emb[ii * 256 + c];
    const float s  = e - zv;                  // fl(z_q - z)
    out_zq[b * 262144 + c * 1024 + hw] = zv + s;  // fl(z + fl(z_q - z)), f32
  }
}

// ---------------- K4: loss output, f32, [b,h,w,c] layout (LDS transpose) ----------------
__global__ void k_loss(const float* __restrict__ z, const float* __restrict__ emb,
                       const int* __restrict__ idx32, float* __restrict__ out_loss){
  __shared__ float zt[256][33];
  __shared__ int   li[32];
  const int bid = blockIdx.x;                 // 512 = 16 b * 32 h
  const int b = bid >> 5, h = bid & 31;
  const int t = threadIdx.x;
  const float* zp = z + b * 262144 + h * 32;
  #pragma unroll 4
  for (int l = 0; l < 32; ++l){
    const int idx = t + 256 * l;              // 8192 = 256 c * 32 w
    const int c = idx >> 5, w = idx & 31;
    zt[c][w] = zp[c * 1024 + w];
  }
  if (t < 32) li[t] = idx32[b * 1024 + h * 32 + t] & (KCODES - 1);
  __syncthreads();
  const int c = t;
  const long obase = (long)((b * 32 + h) * 32) * 256;
  for (int w = 0; w < 32; ++w){
    const float zv = zt[c][w];
    const float e  = emb[li[w] * 256 + c];
    const float s  = e - zv;                  // fl(z_q - z)
    const float t2 = s * s;                   // fl(s^2)
    out_loss[obase + (long)w * 256 + c] = 0.25f * t2 + t2;  // 0.25*t2 exact; one rounding
  }
}

extern "C" void kernel_launch(void* const* d_in, const int* in_sizes, int n_in,
                              void* d_out, int out_size, void* d_ws, size_t ws_size,
                              hipStream_t stream) {
  const float* z   = (const float*)d_in[0];
  const float* emb = (const float*)d_in[1];

  float* out      = (float*)d_out;            // FLOAT32 output buffer
  float* out_zq   = out;                      // z_q   4194304 f32 @ 0
  float* out_loss = out + 4194304;            // loss  4194304 f32 @ 4194304
  float* out_idx  = out + 8388608;            // idx     16384 f32 @ 8388608

  float* zzp   = (float*)d_ws;                // 16384 f32
  float* eep   = zzp + NROWS;                 // 8192 f32
  int*   idx32 = (int*)(eep + KCODES);        // 16384 i32
  float* candd = (float*)(idx32 + NROWS);     // 16384*4 f32
  int*   candi = (int*)(candd + NROWS * 4);   // 16384*4 i32  (total ws use: 688,128 B)

  k_zz    <<<256, 256, 0, stream>>>(z, zzp);
  k_ee    <<<2048, 256, 0, stream>>>(emb, eep);
  k_argmin<<<512, 256, 0, stream>>>(z, emb, zzp, eep, candd, candi);
  k_pick  <<<64, 256, 0, stream>>>(candd, candi, idx32, out_idx);
  k_zq    <<<4096, 256, 0, stream>>>(z, emb, idx32, out_zq);
  k_loss  <<<512, 256, 0, stream>>>(z, emb, idx32, out_loss);
}

// Round 6
// 1389.703 us; speedup vs baseline: 3.2290x; 3.2290x over previous
//
#include <hip/hip_runtime.h>
#include <hip/hip_bf16.h>

// VQ: z [16,256,32,32] f32, emb [8192,256] f32.
// N = 16384 rows (b,h,w), C = 256, K = 8192.
// d_out FLOAT32: z_q @0, loss @4194304, idx (as f32) @8388608.

#define NROWS 16384
#define KCODES 8192

// ---------------- K0a: zz[n] = sum_c z[n][c]^2 ----------------
__global__ void k_zz(const float* __restrict__ z, float* __restrict__ zz){
  __shared__ float p[256];
  const int t  = threadIdx.x;
  const int nl = t & 63, q = t >> 6;
  const int n  = blockIdx.x * 64 + nl;
  const int b  = n >> 10, hw = n & 1023;
  const float* zp = z + b * 262144 + hw;
  float s = 0.f;
  const int c0 = q * 64;
  #pragma unroll 8
  for (int i = 0; i < 64; ++i){
    float v = zp[(c0 + i) * 1024];
    s = fmaf(v, v, s);
  }
  p[t] = s;
  __syncthreads();
  if (q == 0){
    float tot = ((p[nl] + p[nl + 64]) + p[nl + 128]) + p[nl + 192];
    zz[n] = tot;
  }
}

// ---------------- K0b: ee[k] = sum_c emb[k][c]^2 ----------------
__global__ void k_ee(const float* __restrict__ emb, float* __restrict__ ee){
  const int t = threadIdx.x;
  const int k = blockIdx.x * 4 + (t >> 6);
  const int lane = t & 63;
  const float* ep = emb + k * 256;
  float s = 0.f;
  #pragma unroll
  for (int j = 0; j < 4; ++j){
    float v = ep[lane + 64 * j];
    s = fmaf(v, v, s);
  }
  #pragma unroll
  for (int off = 32; off; off >>= 1) s += __shfl_down(s, off);
  if (lane == 0) ee[k] = s;
}

// ---------------- K1: argmin over codes ----------------
// 512 blocks: rowblock = bid>>2 (128 rows), quarter = bid&3 (2048 codes).
// 256 threads: tx = tid&15 (codes, 8 each), ty = tid>>4 (rows, 8 each).
// __launch_bounds__(256,2): 2 blocks/CU, VGPR cap 256 -> NO scratch spill of acc.
__global__ __launch_bounds__(256, 2)
void k_argmin(const float* __restrict__ z, const float* __restrict__ emb,
              const float* __restrict__ zz, const float* __restrict__ ee,
              float* __restrict__ candd, int* __restrict__ candi){
  __shared__ float zs[128][36];
  __shared__ float es[128][36];

  const int tid = threadIdx.x;
  const int bid = blockIdx.x;
  const int rowblock = bid >> 2;
  const int quarter  = bid & 3;
  const int n0     = rowblock * 128;
  const int k0base = quarter * 2048;
  const int tx = tid & 15, ty = tid >> 4;

  const int b = n0 >> 10, hw0 = n0 & 1023;      // all 128 rows share b (128 | 1024)
  const float* zb = z + b * 262144 + hw0;       // + c*1024 + r

  float acc[8][8];
  float best[8];
  int   bidx[8];
  float zzr[8];
  #pragma unroll
  for (int i = 0; i < 8; ++i){
    best[i] = 3.0e38f; bidx[i] = 0;
    zzr[i]  = zz[n0 + ty * 8 + i];
    #pragma unroll
    for (int j = 0; j < 8; ++j) acc[i][j] = 0.f;
  }

  for (int kt = 0; kt < 16; ++kt){
    const int kk0 = k0base + kt * 128;
    for (int cc = 0; cc < 8; ++cc){
      const int cbase = cc * 32;
      float4 zr[4], er[4];
      #pragma unroll
      for (int l = 0; l < 4; ++l){
        const int idx = tid + 256 * l;
        const int c = idx >> 5, ng = idx & 31;
        zr[l] = *reinterpret_cast<const float4*>(zb + (cbase + c) * 1024 + ng * 4);
      }
      #pragma unroll
      for (int l = 0; l < 4; ++l){
        const int idx = tid + 256 * l;
        const int k = idx >> 3, cg = idx & 7;
        er[l] = *reinterpret_cast<const float4*>(emb + (kk0 + k) * 256 + cbase + cg * 4);
      }
      __syncthreads();
      #pragma unroll
      for (int l = 0; l < 4; ++l){
        const int idx = tid + 256 * l;
        const int c = idx >> 5, ng = idx & 31;
        const float v[4] = {zr[l].x, zr[l].y, zr[l].z, zr[l].w};
        #pragma unroll
        for (int m = 0; m < 4; ++m){
          const int r = ng * 4 + m;
          const int g = (r >> 2) & 7;
          zs[r][4 * ((c >> 2) ^ g) + (c & 3)] = v[m];
        }
      }
      #pragma unroll
      for (int l = 0; l < 4; ++l){
        const int idx = tid + 256 * l;
        const int k = idx >> 3, cg = idx & 7;
        const int cgs = cg ^ ((k >> 3) & 7);
        *reinterpret_cast<float4*>(&es[k][cgs * 4]) = er[l];
      }
      __syncthreads();
      // compute: ev[8] resident (32 VGPR), zv streamed (4 VGPR), acc (64 VGPR).
      #pragma unroll
      for (int s4 = 0; s4 < 8; ++s4){
        float4 ev[8];
        #pragma unroll
        for (int j = 0; j < 8; ++j){
          const int k = tx * 8 + j;
          ev[j] = *reinterpret_cast<const float4*>(&es[k][4 * (s4 ^ (tx & 7))]);
        }
        #pragma unroll
        for (int i = 0; i < 8; ++i){
          const int r = ty * 8 + i;
          const int g = (r >> 2) & 7;
          const float4 zv = *reinterpret_cast<const float4*>(&zs[r][4 * (s4 ^ g)]);
          #pragma unroll
          for (int j = 0; j < 8; ++j){
            float a = acc[i][j];
            a = fmaf(zv.x, ev[j].x, a);
            a = fmaf(zv.y, ev[j].y, a);
            a = fmaf(zv.z, ev[j].z, a);
            a = fmaf(zv.w, ev[j].w, a);
            acc[i][j] = a;
          }
        }
      }
    }
    // distances + running argmin for this k-tile
    float eeg[8];
    #pragma unroll
    for (int j = 0; j < 8; ++j) eeg[j] = ee[kk0 + tx * 8 + j];
    #pragma unroll
    for (int i = 0; i < 8; ++i){
      #pragma unroll
      for (int j = 0; j < 8; ++j){
        // EXACT reference op order: fl(fl(zz+ee) - fl(2*dot)); 2*dot exact.
        const float t1 = zzr[i] + eeg[j];
        const float d  = t1 - 2.0f * acc[i][j];
        const int kidx = kk0 + tx * 8 + j;
        if (d < best[i]) { best[i] = d; bidx[i] = kidx; }  // strict <: lowest index wins ties
        acc[i][j] = 0.f;
      }
    }
  }

  // cross-tx reduction per row (16 candidates/row), tie -> lower index
  __syncthreads();
  float* redd = &zs[0][0];
  int*   redi = reinterpret_cast<int*>(&es[0][0]);
  #pragma unroll
  for (int i = 0; i < 8; ++i){
    const int r = ty * 8 + i;
    redd[r * 16 + tx] = best[i];
    redi[r * 16 + tx] = bidx[i];
  }
  __syncthreads();
  if (tid < 128){
    const int r = tid;
    float bd = redd[r * 16];
    int   bi = redi[r * 16];
    #pragma unroll
    for (int t2 = 1; t2 < 16; ++t2){
      const float d = redd[r * 16 + t2];
      const int  ii = redi[r * 16 + t2];
      if (d < bd || (d == bd && ii < bi)) { bd = d; bi = ii; }
    }
    candd[(n0 + r) * 4 + quarter] = bd;
    candi[(n0 + r) * 4 + quarter] = bi;
  }
}

// ---------------- K2: pick winner across 4 K-quarters ----------------
__global__ void k_pick(const float* __restrict__ candd, const int* __restrict__ candi,
                       int* __restrict__ idx32, float* __restrict__ out_idx){
  const int n = blockIdx.x * 256 + threadIdx.x;
  float bd = candd[n * 4];
  int   bi = candi[n * 4];
  #pragma unroll
  for (int t = 1; t < 4; ++t){
    const float d = candd[n * 4 + t];
    const int  ii = candi[n * 4 + t];
    if (d < bd) { bd = d; bi = ii; }   // quarters ascend in k: tie keeps lower index
  }
  bi &= (KCODES - 1);
  idx32[n] = bi;
  out_idx[n] = (float)bi;
}

// ---------------- K3: z_q output, f32, [b,c,h,w] layout ----------------
__global__ void k_zq(const float* __restrict__ z, const float* __restrict__ emb,
                     const int* __restrict__ idx32, float* __restrict__ out_zq){
  const int bid = blockIdx.x;                 // 4096 = 16 b * 256 c
  const int b = bid >> 8, c = bid & 255;
  const int t = threadIdx.x;
  const float* zp = z + b * 262144 + c * 1024;
  #pragma unroll
  for (int l = 0; l < 4; ++l){
    const int hw = t + 256 * l;
    const float zv = zp[hw];
    const int  ii  = idx32[b * 1024 + hw] & (KCODES - 1);
    const float e  = emb[ii * 256 + c];
    const float s  = e - zv;                  // fl(z_q - z)
    out_zq[b * 262144 + c * 1024 + hw] = zv + s;  // fl(z + fl(z_q - z))
  }
}

// ---------------- K4: loss output, f32, [b,h,w,c] layout (LDS transpose) ----------------
__global__ void k_loss(const float* __restrict__ z, const float* __restrict__ emb,
                       const int* __restrict__ idx32, float* __restrict__ out_loss){
  __shared__ float zt[256][33];
  __shared__ int   li[32];
  const int bid = blockIdx.x;                 // 512 = 16 b * 32 h
  const int b = bid >> 5, h = bid & 31;
  const int t = threadIdx.x;
  const float* zp = z + b * 262144 + h * 32;
  #pragma unroll 4
  for (int l = 0; l < 32; ++l){
    const int idx = t + 256 * l;              // 8192 = 256 c * 32 w
    const int c = idx >> 5, w = idx & 31;
    zt[c][w] = zp[c * 1024 + w];
  }
  if (t < 32) li[t] = idx32[b * 1024 + h * 32 + t] & (KCODES - 1);
  __syncthreads();
  const int c = t;
  const long obase = (long)((b * 32 + h) * 32) * 256;
  for (int w = 0; w < 32; ++w){
    const float zv = zt[c][w];
    const float e  = emb[li[w] * 256 + c];
    const float s  = e - zv;                  // fl(z_q - z)
    const float t2 = s * s;                   // fl(s^2)
    out_loss[obase + (long)w * 256 + c] = 0.25f * t2 + t2;  // 0.25*t2 exact; one rounding
  }
}

extern "C" void kernel_launch(void* const* d_in, const int* in_sizes, int n_in,
                              void* d_out, int out_size, void* d_ws, size_t ws_size,
                              hipStream_t stream) {
  const float* z   = (const float*)d_in[0];
  const float* emb = (const float*)d_in[1];

  float* out      = (float*)d_out;            // FLOAT32 output buffer
  float* out_zq   = out;                      // z_q   4194304 f32 @ 0
  float* out_loss = out + 4194304;            // loss  4194304 f32 @ 4194304
  float* out_idx  = out + 8388608;            // idx     16384 f32 @ 8388608

  float* zzp   = (float*)d_ws;                // 16384 f32
  float* eep   = zzp + NROWS;                 // 8192 f32
  int*   idx32 = (int*)(eep + KCODES);        // 16384 i32
  float* candd = (float*)(idx32 + NROWS);     // 16384*4 f32
  int*   candi = (int*)(candd + NROWS * 4);   // 16384*4 i32

  k_zz    <<<256, 256, 0, stream>>>(z, zzp);
  k_ee    <<<2048, 256, 0, stream>>>(emb, eep);
  k_argmin<<<512, 256, 0, stream>>>(z, emb, zzp, eep, candd, candi);
  k_pick  <<<64, 256, 0, stream>>>(candd, candi, idx32, out_idx);
  k_zq    <<<4096, 256, 0, stream>>>(z, emb, idx32, out_zq);
  k_loss  <<<512, 256, 0, stream>>>(z, emb, idx32, out_loss);
}

// Round 7
// 1185.171 us; speedup vs baseline: 3.7862x; 1.1726x over previous
//
#include <hip/hip_runtime.h>
#include <hip/hip_bf16.h>

// VQ: z [16,256,32,32] f32, emb [8192,256] f32.
// N = 16384 rows (b,h,w), C = 256, K = 8192.
// d_out FLOAT32: z_q @0, loss @4194304, idx (as f32) @8388608.

#define NROWS 16384
#define KCODES 8192

// ---------------- K0a: zz[n] = sum_c z[n][c]^2 ----------------
__global__ void k_zz(const float* __restrict__ z, float* __restrict__ zz){
  __shared__ float p[256];
  const int t  = threadIdx.x;
  const int nl = t & 63, q = t >> 6;
  const int n  = blockIdx.x * 64 + nl;
  const int b  = n >> 10, hw = n & 1023;
  const float* zp = z + b * 262144 + hw;
  float s = 0.f;
  const int c0 = q * 64;
  #pragma unroll 8
  for (int i = 0; i < 64; ++i){
    float v = zp[(c0 + i) * 1024];
    s = fmaf(v, v, s);
  }
  p[t] = s;
  __syncthreads();
  if (q == 0){
    float tot = ((p[nl] + p[nl + 64]) + p[nl + 128]) + p[nl + 192];
    zz[n] = tot;
  }
}

// ---------------- K0b: ee[k] = sum_c emb[k][c]^2 ----------------
__global__ void k_ee(const float* __restrict__ emb, float* __restrict__ ee){
  const int t = threadIdx.x;
  const int k = blockIdx.x * 4 + (t >> 6);
  const int lane = t & 63;
  const float* ep = emb + k * 256;
  float s = 0.f;
  #pragma unroll
  for (int j = 0; j < 4; ++j){
    float v = ep[lane + 64 * j];
    s = fmaf(v, v, s);
  }
  #pragma unroll
  for (int off = 32; off; off >>= 1) s += __shfl_down(s, off);
  if (lane == 0) ee[k] = s;
}

// ---------------- K1: argmin over codes ----------------
// 512 blocks: rowblock = bid>>2 (128 rows), quarter = bid&3 (2048 codes).
// 256 threads: tx = tid&15 (codes, 8 each), ty = tid>>4 (rows, 8 each).
// __launch_bounds__(256,1): VGPR cap 512 -> compiler free to allocate ~170, no spill.
// zs swizzle: g(r) = ((r>>2)&7) ^ ((r>>5)&3) -- includes ng's high bits so
// write banks spread 2-way (was 4-way); within a wave r>>5 is constant on the
// read side, so reads stay conflict-free.
__global__ __launch_bounds__(256, 1)
void k_argmin(const float* __restrict__ z, const float* __restrict__ emb,
              const float* __restrict__ zz, const float* __restrict__ ee,
              float* __restrict__ candd, int* __restrict__ candi){
  __shared__ float zs[128][36];
  __shared__ float es[128][36];

  const int tid = threadIdx.x;
  const int bid = blockIdx.x;
  const int rowblock = bid >> 2;
  const int quarter  = bid & 3;
  const int n0     = rowblock * 128;
  const int k0base = quarter * 2048;
  const int tx = tid & 15, ty = tid >> 4;

  const int b = n0 >> 10, hw0 = n0 & 1023;      // all 128 rows share b (128 | 1024)
  const float* zb = z + b * 262144 + hw0;       // + c*1024 + r

  float acc[8][8];
  float best[8];
  int   bidx[8];
  float zzr[8];
  #pragma unroll
  for (int i = 0; i < 8; ++i){
    best[i] = 3.0e38f; bidx[i] = 0;
    zzr[i]  = zz[n0 + ty * 8 + i];
    #pragma unroll
    for (int j = 0; j < 8; ++j) acc[i][j] = 0.f;
  }

  for (int kt = 0; kt < 16; ++kt){
    const int kk0 = k0base + kt * 128;
    for (int cc = 0; cc < 8; ++cc){
      const int cbase = cc * 32;
      float4 zr[4], er[4];
      #pragma unroll
      for (int l = 0; l < 4; ++l){
        const int idx = tid + 256 * l;
        const int c = idx >> 5, ng = idx & 31;
        zr[l] = *reinterpret_cast<const float4*>(zb + (cbase + c) * 1024 + ng * 4);
      }
      #pragma unroll
      for (int l = 0; l < 4; ++l){
        const int idx = tid + 256 * l;
        const int k = idx >> 3, cg = idx & 7;
        er[l] = *reinterpret_cast<const float4*>(emb + (kk0 + k) * 256 + cbase + cg * 4);
      }
      __syncthreads();
      #pragma unroll
      for (int l = 0; l < 4; ++l){
        const int idx = tid + 256 * l;
        const int c = idx >> 5, ng = idx & 31;
        const float v[4] = {zr[l].x, zr[l].y, zr[l].z, zr[l].w};
        #pragma unroll
        for (int m = 0; m < 4; ++m){
          const int r = ng * 4 + m;
          const int g = ((r >> 2) & 7) ^ ((r >> 5) & 3);
          zs[r][4 * ((c >> 2) ^ g) + (c & 3)] = v[m];
        }
      }
      #pragma unroll
      for (int l = 0; l < 4; ++l){
        const int idx = tid + 256 * l;
        const int k = idx >> 3, cg = idx & 7;
        const int cgs = cg ^ ((k >> 3) & 7);
        *reinterpret_cast<float4*>(&es[k][cgs * 4]) = er[l];
      }
      __syncthreads();
      // compute: ev[8] resident (32 VGPR), zv streamed (4 VGPR), acc (64 VGPR).
      #pragma unroll
      for (int s4 = 0; s4 < 8; ++s4){
        float4 ev[8];
        #pragma unroll
        for (int j = 0; j < 8; ++j){
          const int k = tx * 8 + j;
          ev[j] = *reinterpret_cast<const float4*>(&es[k][4 * (s4 ^ (tx & 7))]);
        }
        #pragma unroll
        for (int i = 0; i < 8; ++i){
          const int r = ty * 8 + i;
          const int g = ((r >> 2) & 7) ^ ((r >> 5) & 3);
          const float4 zv = *reinterpret_cast<const float4*>(&zs[r][4 * (s4 ^ g)]);
          #pragma unroll
          for (int j = 0; j < 8; ++j){
            float a = acc[i][j];
            a = fmaf(zv.x, ev[j].x, a);
            a = fmaf(zv.y, ev[j].y, a);
            a = fmaf(zv.z, ev[j].z, a);
            a = fmaf(zv.w, ev[j].w, a);
            acc[i][j] = a;
          }
        }
      }
    }
    // distances + running argmin for this k-tile
    float eeg[8];
    #pragma unroll
    for (int j = 0; j < 8; ++j) eeg[j] = ee[kk0 + tx * 8 + j];
    #pragma unroll
    for (int i = 0; i < 8; ++i){
      #pragma unroll
      for (int j = 0; j < 8; ++j){
        // EXACT reference op order: fl(fl(zz+ee) - fl(2*dot)); 2*dot exact.
        const float t1 = zzr[i] + eeg[j];
        const float d  = t1 - 2.0f * acc[i][j];
        const int kidx = kk0 + tx * 8 + j;
        if (d < best[i]) { best[i] = d; bidx[i] = kidx; }  // strict <: lowest index wins ties
        acc[i][j] = 0.f;
      }
    }
  }

  // cross-tx reduction per row (16 candidates/row), tie -> lower index
  __syncthreads();
  float* redd = &zs[0][0];
  int*   redi = reinterpret_cast<int*>(&es[0][0]);
  #pragma unroll
  for (int i = 0; i < 8; ++i){
    const int r = ty * 8 + i;
    redd[r * 16 + tx] = best[i];
    redi[r * 16 + tx] = bidx[i];
  }
  __syncthreads();
  if (tid < 128){
    const int r = tid;
    float bd = redd[r * 16];
    int   bi = redi[r * 16];
    #pragma unroll
    for (int t2 = 1; t2 < 16; ++t2){
      const float d = redd[r * 16 + t2];
      const int  ii = redi[r * 16 + t2];
      if (d < bd || (d == bd && ii < bi)) { bd = d; bi = ii; }
    }
    candd[(n0 + r) * 4 + quarter] = bd;
    candi[(n0 + r) * 4 + quarter] = bi;
  }
}

// ---------------- K2: pick winner across 4 K-quarters ----------------
__global__ void k_pick(const float* __restrict__ candd, const int* __restrict__ candi,
                       int* __restrict__ idx32, float* __restrict__ out_idx){
  const int n = blockIdx.x * 256 + threadIdx.x;
  float bd = candd[n * 4];
  int   bi = candi[n * 4];
  #pragma unroll
  for (int t = 1; t < 4; ++t){
    const float d = candd[n * 4 + t];
    const int  ii = candi[n * 4 + t];
    if (d < bd) { bd = d; bi = ii; }   // quarters ascend in k: tie keeps lower index
  }
  bi &= (KCODES - 1);
  idx32[n] = bi;
  out_idx[n] = (float)bi;
}

// ---------------- K3: z_q output, f32, [b,c,h,w] layout ----------------
__global__ void k_zq(const float* __restrict__ z, const float* __restrict__ emb,
                     const int* __restrict__ idx32, float* __restrict__ out_zq){
  const int bid = blockIdx.x;                 // 4096 = 16 b * 256 c
  const int b = bid >> 8, c = bid & 255;
  const int t = threadIdx.x;
  const float* zp = z + b * 262144 + c * 1024;
  #pragma unroll
  for (int l = 0; l < 4; ++l){
    const int hw = t + 256 * l;
    const float zv = zp[hw];
    const int  ii  = idx32[b * 1024 + hw] & (KCODES - 1);
    const float e  = emb[ii * 256 + c];
    const float s  = e - zv;                  // fl(z_q - z)
    out_zq[b * 262144 + c * 1024 + hw] = zv + s;  // fl(z + fl(z_q - z))
  }
}

// ---------------- K4: loss output, f32, [b,h,w,c] layout (LDS transpose) ----------------
__global__ void k_loss(const float* __restrict__ z, const float* __restrict__ emb,
                       const int* __restrict__ idx32, float* __restrict__ out_loss){
  __shared__ float zt[256][33];
  __shared__ int   li[32];
  const int bid = blockIdx.x;                 // 512 = 16 b * 32 h
  const int b = bid >> 5, h = bid & 31;
  const int t = threadIdx.x;
  const float* zp = z + b * 262144 + h * 32;
  #pragma unroll 4
  for (int l = 0; l < 32; ++l){
    const int idx = t + 256 * l;              // 8192 = 256 c * 32 w
    const int c = idx >> 5, w = idx & 31;
    zt[c][w] = zp[c * 1024 + w];
  }
  if (t < 32) li[t] = idx32[b * 1024 + h * 32 + t] & (KCODES - 1);
  __syncthreads();
  const int c = t;
  const long obase = (long)((b * 32 + h) * 32) * 256;
  for (int w = 0; w < 32; ++w){
    const float zv = zt[c][w];
    const float e  = emb[li[w] * 256 + c];
    const float s  = e - zv;                  // fl(z_q - z)
    const float t2 = s * s;                   // fl(s^2)
    out_loss[obase + (long)w * 256 + c] = 0.25f * t2 + t2;  // 0.25*t2 exact; one rounding
  }
}

extern "C" void kernel_launch(void* const* d_in, const int* in_sizes, int n_in,
                              void* d_out, int out_size, void* d_ws, size_t ws_size,
                              hipStream_t stream) {
  const float* z   = (const float*)d_in[0];
  const float* emb = (const float*)d_in[1];

  float* out      = (float*)d_out;            // FLOAT32 output buffer
  float* out_zq   = out;                      // z_q   4194304 f32 @ 0
  float* out_loss = out + 4194304;            // loss  4194304 f32 @ 4194304
  float* out_idx  = out + 8388608;            // idx     16384 f32 @ 8388608

  float* zzp   = (float*)d_ws;                // 16384 f32
  float* eep   = zzp + NROWS;                 // 8192 f32
  int*   idx32 = (int*)(eep + KCODES);        // 16384 i32
  float* candd = (float*)(idx32 + NROWS);     // 16384*4 f32
  int*   candi = (int*)(candd + NROWS * 4);   // 16384*4 i32

  k_zz    <<<256, 256, 0, stream>>>(z, zzp);
  k_ee    <<<2048, 256, 0, stream>>>(emb, eep);
  k_argmin<<<512, 256, 0, stream>>>(z, emb, zzp, eep, candd, candi);
  k_pick  <<<64, 256, 0, stream>>>(candd, candi, idx32, out_idx);
  k_zq    <<<4096, 256, 0, stream>>>(z, emb, idx32, out_zq);
  k_loss  <<<512, 256, 0, stream>>>(z, emb, idx32, out_loss);
}